// Round 1
// baseline (377.870 us; speedup 1.0000x reference)
//
#include <hip/hip_runtime.h>

// PatientMeanEncoder: causal nonzero-mean pool over concat(timesteps, MLP(dem)).
// N=64, L=2048, C_IN=256, DEM=10, hidden 40 -> 20, C_OUT = 256+20 = 276.
//
// Channels >= 256 carry a constant v = dem_emb[n,j] >= 0 along l, so the causal
// nonzero-mean of them is just v itself (v>0: (l+1)v/(l+1)=v; v==0: 0/max(0,1)=0).
// Only the 256 timesteps channels need the sequential (sum, count) scan.

#define NB 64
#define LL 2048
#define CIN 256
#define COUT 276
#define DEMD 10
#define H1 40
#define H2 20

__global__ __launch_bounds__(64) void pme_kernel(
    const float* __restrict__ ts,   // (N, L, 256)
    const float* __restrict__ dem,  // (N, 10)
    const float* __restrict__ W1,   // (10, 40)
    const float* __restrict__ b1,   // (40,)
    const float* __restrict__ W2,   // (40, 20)
    const float* __restrict__ b2,   // (20,)
    float* __restrict__ out)        // (N, L, 276)
{
    const int bid  = blockIdx.x;
    const int n    = bid / 5;
    const int part = bid % 5;      // 0..3: timesteps c-tiles; 4: dem channels
    const int lane = threadIdx.x;  // 0..63

    if (part < 4) {
        // ---- causal nonzero-mean scan over one channel ----
        const int c = part * 64 + lane;
        const float* tp = ts  + (size_t)n * LL * CIN  + c;
        float*       op = out + (size_t)n * LL * COUT + c;

        float acc = 0.0f;   // running sum
        float cnt = 0.0f;   // running nonzero count

        constexpr int U = 32;  // independent loads in flight to hide HBM latency
        for (int l0 = 0; l0 < LL; l0 += U) {
            float v[U];
#pragma unroll
            for (int u = 0; u < U; ++u)
                v[u] = tp[(size_t)(l0 + u) * CIN];
#pragma unroll
            for (int u = 0; u < U; ++u) {
                acc += v[u];
                cnt += (v[u] != 0.0f) ? 1.0f : 0.0f;
                float p = acc / fmaxf(cnt, 1.0f);
                op[(size_t)(l0 + u) * COUT] = fmaxf(p, 0.0f);
            }
        }
    } else {
        // ---- dem MLP (tiny, recomputed per n-block) + broadcast ----
        if (lane < H2) {
            const int j = lane;
            const float* dn = dem + n * DEMD;
            float o = b2[j];
#pragma unroll
            for (int k = 0; k < H1; ++k) {
                float hk = b1[k];
#pragma unroll
                for (int i = 0; i < DEMD; ++i)
                    hk += dn[i] * W1[i * H1 + k];
                hk = fmaxf(hk, 0.0f);
                o += hk * W2[k * H2 + j];
            }
            const float e = fmaxf(o, 0.0f);  // == output for this channel at every l

            float* op = out + (size_t)n * LL * COUT + CIN + j;
#pragma unroll 8
            for (int l = 0; l < LL; ++l)
                op[(size_t)l * COUT] = e;
        }
    }
}

extern "C" void kernel_launch(void* const* d_in, const int* in_sizes, int n_in,
                              void* d_out, int out_size, void* d_ws, size_t ws_size,
                              hipStream_t stream) {
    const float* ts  = (const float*)d_in[0];
    const float* dem = (const float*)d_in[1];
    const float* W1  = (const float*)d_in[2];
    const float* b1  = (const float*)d_in[3];
    const float* W2  = (const float*)d_in[4];
    const float* b2  = (const float*)d_in[5];
    float* out = (float*)d_out;

    pme_kernel<<<NB * 5, 64, 0, stream>>>(ts, dem, W1, b1, W2, b2, out);
}